// Round 9
// baseline (245.683 us; speedup 1.0000x reference)
//
#include <hip/hip_runtime.h>

// LDPC neural BP decoder, MI355X. Round 19.
// Cross-round fact: SQ_LDS_BANK_CONFLICT = 1.703e7 for b64-f32 AND b32-f16 ->
// conflicts are INDEX-determined (bank-pair = node%16), worth ~66K cyc/CU =
// the largest removable LDS term (R14 is LDS-saturated: ~100K base + 66K).
// R18's f16 log-domain cut LDS bytes but doubled trans-VALU (125K cyc) ->
// net loss vs R14 (88.6 vs 79us). The 64-VGPR cap is immovable (5 rounds).
// This round: R14's proven f32-linear-b64 math (minus wllr[], per R18) +
// SLOT-SCHEDULED offsets: the check product is order-invariant, so prep
// permutes each node's 10 slots to balance per-gather bank-pair loads within
// each 64-node wave group. 3 rounds of greedy pairwise swaps (power-of-two-
// choices) vs 4-bit bank-pair counters in registers (statically indexed).
// Expected max pair-load 8 -> ~5 => conflict ~66K -> ~15-25K cyc/CU.
// Predict: BANK_CONFLICT 1.703e7 -> 0.5-0.9e7 (signature; unchanged => model
// wrong, abandon), decode 79 -> 60-68us, VALUBusy 45-50%, total ~132-142.

#define NN    8448
#define MAXNB 10
#define TPB   1024
#define MAXK  9       // ceil(8448/1024)
#define ITERS 5
#define NG    (NN / 64)                     // 132 wave-groups
#define TBL_BYTES  (NN * 8)                 // 67584: v2f per node
#define LDS_BYTES  (2 * TBL_BYTES)          // 135168: double-buffered, static
#define OFFS_INTS  12                       // 10 byte-offs + {wr0,wr1} bits
#define OFFS_BYTES ((size_t)NN * OFFS_INTS * sizeof(int))   // 405504
#define WS_NEEDED  OFFS_BYTES

typedef float v2f __attribute__((ext_vector_type(2)));

// --- prep: slot-schedule the 10 gathers per node within each 64-node group.
// Bank-pair of a b64 LDS read at byte off idx*8 is idx%16. Greedy pairwise
// swaps (3 disjoint-pair rounds) against accumulated per-column pair counts.
__device__ __forceinline__ unsigned getc(unsigned long long c, int b)
{
    return (unsigned)(c >> (4 * b)) & 15u;
}

__global__ __launch_bounds__(64)
void prep_kernel(const int* __restrict__ cidx, const float* __restrict__ w_res,
                 int* __restrict__ offs)
{
    int g = blockIdx.x * 64 + threadIdx.x;
    if (g >= NG) return;
    const int base = g * 64;
    // 16 bank-pairs x 4-bit counters per column, register-resident
    unsigned long long cnt[MAXNB];
    #pragma unroll
    for (int j = 0; j < MAXNB; ++j) cnt[j] = 0ull;

    constexpr int PA[3][5] = {{0,1,2,3,4},{0,1,4,5,8},{0,2,4,6,8}};
    constexpr int PB[3][5] = {{5,6,7,8,9},{2,3,6,7,9},{1,3,5,7,9}};

    for (int r = 0; r < 64; ++r) {
        int n = base + r;
        int it[MAXNB];
        #pragma unroll
        for (int j = 0; j < MAXNB; ++j) it[j] = cidx[n * MAXNB + j];
        #pragma unroll
        for (int rd = 0; rd < 3; ++rd) {
            #pragma unroll
            for (int p = 0; p < 5; ++p) {
                const int a = PA[rd][p], b = PB[rd][p];
                int ba = it[a] & 15, bb = it[b] & 15;
                unsigned keep = getc(cnt[a], ba) + getc(cnt[b], bb);
                unsigned swp  = getc(cnt[a], bb) + getc(cnt[b], ba);
                if (swp < keep) { int t = it[a]; it[a] = it[b]; it[b] = t; }
            }
        }
        #pragma unroll
        for (int j = 0; j < MAXNB; ++j) {
            cnt[j] += 1ull << (4 * (it[j] & 15));
            offs[n * OFFS_INTS + j] = it[j] * 8;     // byte off of v2f
        }
        offs[n * OFFS_INTS + 10] = __float_as_int(w_res[n]);
        offs[n * OFFS_INTS + 11] = __float_as_int(w_res[NN + n]);
    }
}

// t = tanh(clip(0.5*v, +-9.9)) = 1 - 2/(exp(clip(v,+-19.8))+1), both rows,
// shared reciprocal: r = rcp(A*B); 1/A = r*B; 1/B = r*A.
__device__ __forceinline__ v2f tanh_half(v2f v)
{
    v2f y = __builtin_elementwise_min(
                __builtin_elementwise_max(v, (v2f)(-19.8f)), (v2f)(19.8f));
    v2f e;
    e.x = __expf(y.x);
    e.y = __expf(y.y);
    v2f ab = e + 1.0f;                               // {A,B}
    float r = __builtin_amdgcn_rcpf(ab.x * ab.y);
    v2f ba = ab.yx;                                  // {B,A}
    v2f inv = ba * r;                                // {1/A,1/B}
    return 1.0f - 2.0f * inv;                        // contracts to pk_fma
}

template<bool USE_OFF>
__global__ __launch_bounds__(TPB)
void ldpc_decode_kernel(const float* __restrict__ input_llr,
                        const float* __restrict__ w_ch,
                        const float* __restrict__ w_res,   // [2][NN]
                        const int*   __restrict__ cidx,    // [NN][10]
                        const int*   __restrict__ offs,    // [NN][12]
                        float* __restrict__ out)
{
    __shared__ __align__(16) char smem[LDS_BYTES];   // 1 block/CU
    const int tid  = threadIdx.x;
    const int row0 = blockIdx.x * 2;
    const float* __restrict__ in0 = input_llr + (size_t)row0 * NN;
    const float* __restrict__ in1 = in0 + NN;
    float* __restrict__ out0 = out + (size_t)row0 * NN;
    float* __restrict__ out1 = out0 + NN;

    // persistent state: vm/vmp only (36 VGPRs); wllr recomputed per region
    v2f vm[MAXK], vmp[MAXK];

    // prologue: init state, write t(vm) into buffer 0
    #pragma unroll
    for (int k = 0; k < MAXK; ++k) {
        int n = tid + k * TPB;
        vmp[k] = (v2f)(0.0f);
        vm[k]  = (v2f)(0.0f);
        if (k < MAXK - 1 || n < NN) {
            float wc = w_ch[n];
            v2f x;
            x.x = in0[n];
            x.y = in1[n];
            vm[k] = x * wc;
            *(v2f*)(smem + (size_t)n * 8) = tanh_half(vm[k]);
        }
    }
    __syncthreads();

    #pragma unroll
    for (int it = 0; it < ITERS; ++it) {
        const int rbase = (it & 1) ? TBL_BYTES : 0;  // compile-time per it
        const int wbase = (it & 1) ? 0 : TBL_BYTES;
        #pragma unroll
        for (int k = 0; k < MAXK; ++k) {
            int n = tid + k * TPB;
            if (k < MAXK - 1 || n < NN) {
                int o0, o1, o2, o3, o4, o5, o6, o7, o8, o9;
                float wr0, wr1;
                if (USE_OFF) {
                    const int4* op = (const int4*)(offs + n * OFFS_INTS);
                    int4 oA = op[0];                 // rows are 48B, 16-aligned
                    int4 oB = op[1];
                    int4 oC = op[2];
                    o0 = oA.x; o1 = oA.y; o2 = oA.z; o3 = oA.w;
                    o4 = oB.x; o5 = oB.y; o6 = oB.z; o7 = oB.w;
                    o8 = oC.x; o9 = oC.y;
                    wr0 = __int_as_float(oC.z);
                    wr1 = __int_as_float(oC.w);
                } else {
                    const int2* ip = (const int2*)(cidx + n * MAXNB);
                    int2 i0 = ip[0], i1 = ip[1], i2 = ip[2], i3 = ip[3], i4 = ip[4];
                    o0 = i0.x << 3; o1 = i0.y << 3;
                    o2 = i1.x << 3; o3 = i1.y << 3;
                    o4 = i2.x << 3; o5 = i2.y << 3;
                    o6 = i3.x << 3; o7 = i3.y << 3;
                    o8 = i4.x << 3; o9 = i4.y << 3;
                    wr0 = w_res[n];
                    wr1 = w_res[NN + n];
                }
                const char* __restrict__ rb = smem + rbase;
                v2f g0 = *(const v2f*)(rb + o0);
                v2f g1 = *(const v2f*)(rb + o1);
                v2f g2 = *(const v2f*)(rb + o2);
                v2f g3 = *(const v2f*)(rb + o3);
                v2f g4 = *(const v2f*)(rb + o4);
                v2f g5 = *(const v2f*)(rb + o5);
                v2f g6 = *(const v2f*)(rb + o6);
                v2f g7 = *(const v2f*)(rb + o7);
                v2f g8 = *(const v2f*)(rb + o8);
                v2f g9 = *(const v2f*)(rb + o9);
                // pk product tree: 9 packed muls
                v2f m01 = (g0 * g1) * (g2 * g3);
                v2f m23 = (g4 * g5) * (g6 * g7);
                v2f pr  = (m01 * m23) * (g8 * g9);
                pr = __builtin_elementwise_min(
                         __builtin_elementwise_max(pr, (v2f)(-0.999999f)),
                         (v2f)(0.999999f));
                v2f num = 1.0f + pr;                     // pk_add
                v2f den = 1.0f - pr;                     // pk_sub
                v2f check;
                check.x = 0.69314718f * (__log2f(num.x) - __log2f(den.x));
                check.y = 0.69314718f * (__log2f(num.y) - __log2f(den.y));
                // nv = in*wc + check + wr0*vm + wr1*vmp  (wllr recomputed)
                float wc = w_ch[n];
                v2f x;
                x.x = in0[n];
                x.y = in1[n];
                v2f res = vm[k] * wr0 + vmp[k] * wr1;    // pk_fma
                v2f nv  = (x * wc + check) + res;
                vmp[k] = vm[k];
                vm[k]  = nv;
                if (it < ITERS - 1) {
                    *(v2f*)(smem + wbase + (size_t)n * 8) = tanh_half(nv);
                }
            }
            // fence: cap per-region register pressure
            __builtin_amdgcn_sched_barrier(0);
        }
        if (it < ITERS - 1) __syncthreads();              // one barrier per iter
    }

    // epilogue: sigmoid(vm + input)
    #pragma unroll
    for (int k = 0; k < MAXK; ++k) {
        int n = tid + k * TPB;
        if (k < MAXK - 1 || n < NN) {
            float x0 = vm[k].x + in0[n];
            float x1 = vm[k].y + in1[n];
            out0[n] = __fdividef(1.0f, 1.0f + __expf(-x0));
            out1[n] = __fdividef(1.0f, 1.0f + __expf(-x1));
        }
    }
}

extern "C" void kernel_launch(void* const* d_in, const int* in_sizes, int n_in,
                              void* d_out, int out_size, void* d_ws, size_t ws_size,
                              hipStream_t stream) {
    const float* input_llr = (const float*)d_in[0];
    const float* w_ch      = (const float*)d_in[1];
    const float* w_res     = (const float*)d_in[2];
    const int*   cidx      = (const int*)d_in[3];
    // d_in[4] (var_index_tensor) is unused by the reference
    float* out = (float*)d_out;
    int batch = in_sizes[0] / NN;
    const bool use_off = (ws_size >= WS_NEEDED) && (d_ws != nullptr);

    if (use_off) {
        int* offs = (int*)d_ws;
        hipLaunchKernelGGL(prep_kernel, dim3((NG + 63) / 64), dim3(64), 0,
                           stream, cidx, w_res, offs);
        hipLaunchKernelGGL(ldpc_decode_kernel<true>, dim3(batch / 2), dim3(TPB),
                           0, stream, input_llr, w_ch, w_res, cidx,
                           offs, out);
    } else {
        hipLaunchKernelGGL(ldpc_decode_kernel<false>, dim3(batch / 2), dim3(TPB),
                           0, stream, input_llr, w_ch, w_res, cidx,
                           nullptr, out);
    }
}